// Round 2
// baseline (645.474 us; speedup 1.0000x reference)
//
#include <hip/hip_runtime.h>
#include <cstdint>

#define N_NODES 172032
#define BATCH   8192
#define NPS     21
#define F_IN    171
#define K1P     192      // K padded to multiple of 32 for layer-1 GEMM
#define F_HID   256
#define F_OUT   128
#define SX_F    (NPS * F_IN)   // 3591 floats per sample in x/out_x
#define SXB     (NPS * K1P)    // 4032 bf16 per sample in xb
#define SPB     3              // samples per fused block
#define NBLK    2731           // ceil(8192/3)

typedef unsigned short u16;
typedef __attribute__((ext_vector_type(8))) short  bf16x8;
typedef __attribute__((ext_vector_type(4))) float  f32x4;

__device__ inline u16 f2bf(float f) {
    unsigned u = __float_as_uint(f);
    unsigned r = u + 0x7FFFu + ((u >> 16) & 1u);
    return (u16)(r >> 16);
}
__device__ inline float bf2f(u16 h) { return __uint_as_float(((unsigned)h) << 16); }
__device__ inline float lrelu(float v) { return v > 0.f ? v : 0.2f * v; }

// ---- static edge structure (local node ids within a 21-node sample) ----
// node 0 = query, 1..10 = docs, 11..20 = titles
__device__ inline int deg_of(int n)  { return n == 0 ? 11 : (n <= 10 ? 3 : 2); }
__device__ inline int edge_base(int n) { return n == 0 ? 0 : (n <= 10 ? 11 + 3*(n-1) : 41 + 2*(n-11)); }
__device__ inline int src_of(int n, int k) {
    if (n == 0)  return k < 10 ? k + 1 : 0;
    if (n <= 10) return k == 0 ? 0 : (k == 1 ? n + 10 : n);
    return k == 0 ? n - 10 : n;
}

__device__ inline float wave_red(float v) {
    for (int off = 32; off; off >>= 1) v += __shfl_down(v, off);
    return v;
}

// ------------------------------------------------------------------
// build_x: one block per SAMPLE (blocks < BATCH). Assemble 21x171 fp32
// in LDS from table gathers + x tail, then bulk write: out_x via aligned
// float4, xb via packed 8xbf16 uint4.
// Blocks >= BATCH: weight prep (W1->W1b 256x192 bf16, W2->W2b bf16).
// ------------------------------------------------------------------
__global__ __launch_bounds__(256) void build_x(const int* __restrict__ iptr, const float* __restrict__ x,
                        const int* __restrict__ click, const int* __restrict__ query,
                        const int* __restrict__ docu, const int* __restrict__ title_id,
                        const float* __restrict__ qtab, const float* __restrict__ dtab,
                        const float* __restrict__ ttab, const float* __restrict__ ptab,
                        const float* __restrict__ ctab,
                        const float* __restrict__ W1, const float* __restrict__ W2,
                        float* __restrict__ out_x, u16* __restrict__ xb,
                        u16* __restrict__ W1b, u16* __restrict__ W2b)
{
    if (blockIdx.x >= BATCH) {
        int id = (blockIdx.x - BATCH) * 256 + threadIdx.x;
        if (id < 256 * K1P) {
            int r = id / K1P, k = id - r * K1P;
            W1b[id] = (k < F_IN) ? f2bf(W1[r * F_IN + k]) : (u16)0;
        }
        if (id < 128 * 256) W2b[id] = f2bf(W2[id]);
        return;
    }

    __shared__ float sx[SX_F];
    __shared__ int   dz[10], tz[10], s_q;
    __shared__ float s_clk;

    const int s   = blockIdx.x;
    const int tid = threadIdx.x;
    const int i   = iptr[0];
    const long xbase = (long)s * SX_F;

    if (tid < 10)       dz[tid]      = docu[s*10 + tid];
    else if (tid < 20)  tz[tid - 10] = title_id[s*10 + tid - 10];
    else if (tid == 20) s_q          = query[s];
    else if (tid == 21) s_clk        = ctab[click[s]];
    __syncthreads();

    if (i == 0) {
        for (int idx = tid; idx < SX_F; idx += 256) {
            int p = idx / F_IN;            // compile-time const divisor -> magic mul
            int c = idx - p * F_IN;
            float v;
            if (c >= 160) {
                if (p >= 1 && p <= 10 && c == 160)      v = ptab[p - 1];
                else if (p >= 1 && p <= 10 && c == 161) v = s_clk;
                else                                     v = x[xbase + idx];
            } else {
                if (p == 0)       v = qtab[(long)s_q * 160 + c];
                else if (p <= 10) v = dtab[(long)dz[p-1] * 160 + c];
                else              v = ttab[(long)tz[p-11] * 160 + c];
            }
            sx[idx] = v;
        }
    } else {
        for (int idx = tid; idx < SX_F; idx += 256) {
            int p = idx / F_IN;
            int c = idx - p * F_IN;
            float v = x[xbase + idx];
            if (p >= 1 && p <= 10 && c == 161 + i) v = s_clk;
            sx[idx] = v;
        }
    }
    __syncthreads();

    // ---- out_x: flat region [xbase, xbase+3591), float4 on aligned interior ----
    {
        int r    = (int)(xbase & 3);
        int head = (4 - r) & 3;
        if (tid < head) out_x[xbase + tid] = sx[tid];
        int n4 = (SX_F - head) >> 2;
        for (int id = tid; id < n4; id += 256) {
            int o = head + id * 4;
            float4 v = make_float4(sx[o], sx[o+1], sx[o+2], sx[o+3]);
            *(float4*)(out_x + xbase + o) = v;
        }
        int done = head + n4 * 4;
        int tail = SX_F - done;
        if (tid < tail) out_x[xbase + done + tid] = sx[done + tid];
    }

    // ---- xb: bf16, K-padded to 192/row; sample region 16B-aligned ----
    {
        u16* xbs = xb + (long)s * SXB;
        for (int id = tid; id < SXB / 8; id += 256) {
            int k0 = id * 8;
            int node = k0 / K1P;
            int kk   = k0 - node * K1P;
            union { u16 h[8]; uint4 v; } u;
            #pragma unroll
            for (int j = 0; j < 8; ++j) {
                int c = kk + j;
                u.h[j] = (c < F_IN) ? f2bf(sx[node * F_IN + c]) : (u16)0;
            }
            *(uint4*)(xbs + k0) = u.v;
        }
    }
}

// ------------------------------------------------------------------
// fused1: GEMM (63x192 @ W1b^T -> 63x256) + GAT agg layer 1 + relu.
// One block = 3 samples (64 padded rows). h stays in LDS; only y1b
// (bf16) goes to HBM.
// ------------------------------------------------------------------
__global__ __launch_bounds__(256) void fused1(const u16* __restrict__ xb, const u16* __restrict__ W1b,
                                              const float* __restrict__ asrc, const float* __restrict__ adst,
                                              const float* __restrict__ bias, u16* __restrict__ y1b)
{
    constexpr int KS  = 64;    // K per stage (192 = 3 stages)
    constexpr int SA  = 200;   // A row stride in LDS (192+8)
    constexpr int SB  = 72;    // B row stride in LDS (64+8)
    __shared__ __align__(16) u16 Al[64 * SA];        // 25600 B
    __shared__ __align__(16) u16 Bu[256 * SB];       // 36864 B: B stage, then h (64x256 bf16 = 32768 B)
    __shared__ float s_l[64], d_l[64], alpha[3 * 61];

    const int blk = blockIdx.x, tid = threadIdx.x;
    const int s0  = blk * SPB;
    const int nsamp = (s0 + SPB <= BATCH) ? SPB : (BATCH - s0);
    const int nrow  = nsamp * NPS;

    const int lane = tid & 63, w = tid >> 6;
    const int wr = w >> 1, wc = w & 1;
    const int lm = lane & 15, lq = lane >> 4;

    // ---- stage A (63x192 bf16 rows, zero-pad to 64) ----
    const u16* Ag = xb + (long)s0 * SXB;
    for (int id = tid; id < 64 * (K1P / 8); id += 256) {   // 1536 chunks
        int row = id / 24, ch = id - row * 24;
        uint4 v;
        if (row < nrow) v = *(const uint4*)(Ag + row * K1P + ch * 8);
        else            v = make_uint4(0u, 0u, 0u, 0u);
        *(uint4*)(Al + row * SA + ch * 8) = v;
    }

    f32x4 acc[2][8];
    #pragma unroll
    for (int f = 0; f < 2; ++f)
        #pragma unroll
        for (int g = 0; g < 8; ++g)
            acc[f][g] = (f32x4){0.f, 0.f, 0.f, 0.f};

    for (int ks = 0; ks < K1P; ks += KS) {
        __syncthreads();   // A staged (ks=0) / previous MFMAs done before Bu overwrite
        for (int id = tid; id < 256 * (KS / 8); id += 256) {  // 2048 chunks
            int row = id >> 3, ch = id & 7;
            *(uint4*)(Bu + row * SB + ch * 8) = *(const uint4*)(W1b + row * K1P + ks + ch * 8);
        }
        __syncthreads();
        #pragma unroll
        for (int kb = 0; kb < KS / 32; ++kb) {
            int ka    = ks + kb * 32 + lq * 8;
            int kboff = kb * 32 + lq * 8;
            bf16x8 a0 = *(const bf16x8*)(Al + (wr*32 +  0 + lm) * SA + ka);
            bf16x8 a1 = *(const bf16x8*)(Al + (wr*32 + 16 + lm) * SA + ka);
            #pragma unroll
            for (int g = 0; g < 8; ++g) {
                bf16x8 b = *(const bf16x8*)(Bu + (wc*128 + g*16 + lm) * SB + kboff);
                acc[0][g] = __builtin_amdgcn_mfma_f32_16x16x32_bf16(a0, b, acc[0][g], 0, 0, 0);
                acc[1][g] = __builtin_amdgcn_mfma_f32_16x16x32_bf16(a1, b, acc[1][g], 0, 0, 0);
            }
        }
    }

    __syncthreads();          // Bu (B stage) dead; reuse as h
    u16* h = Bu;              // 64 rows x 256 cols bf16
    #pragma unroll
    for (int f = 0; f < 2; ++f)
        #pragma unroll
        for (int g = 0; g < 8; ++g)
            #pragma unroll
            for (int r = 0; r < 4; ++r) {
                int row = wr*32 + f*16 + lq*4 + r;
                int col = wc*128 + g*16 + lm;
                h[row * F_HID + col] = f2bf(acc[f][g][r]);
            }
    __syncthreads();

    // ---- attention logits: s_l[n] = h[n].a_src, d_l[n] = h[n].a_dst ----
    float av[4], dv[4];
    #pragma unroll
    for (int j = 0; j < 4; ++j) { av[j] = asrc[lane + j*64]; dv[j] = adst[lane + j*64]; }
    for (int n = w; n < nrow; n += 4) {
        float as_ = 0.f, ad_ = 0.f;
        #pragma unroll
        for (int j = 0; j < 4; ++j) {
            float hv = bf2f(h[n * F_HID + lane + j*64]);
            as_ += hv * av[j];
            ad_ += hv * dv[j];
        }
        as_ = wave_red(as_); ad_ = wave_red(ad_);
        if (lane == 0) { s_l[n] = as_; d_l[n] = ad_; }
    }
    __syncthreads();

    // ---- softmax over incoming edges (per destination node) ----
    if (tid < nrow) {
        int s = tid / NPS, p = tid - s * NPS;
        int deg = deg_of(p), eb = edge_base(p);
        const float* sl = s_l + s * NPS;
        float dn = d_l[tid], m = -1e30f;
        for (int k = 0; k < deg; ++k) m = fmaxf(m, lrelu(sl[src_of(p,k)] + dn));
        float den = 0.f;
        for (int k = 0; k < deg; ++k) den += expf(lrelu(sl[src_of(p,k)] + dn) - m);
        float inv = 1.f / den;
        for (int k = 0; k < deg; ++k) alpha[s*61 + eb + k] = expf(lrelu(sl[src_of(p,k)] + dn) - m) * inv;
    }
    __syncthreads();

    // ---- aggregate + bias + relu -> y1b (bf16) ----
    const int c = tid;          // 256 threads = F_HID
    float bc = bias[c];
    for (int s = 0; s < nsamp; ++s) {
        const u16* hs = h + s * NPS * F_HID;
        const float* al = alpha + s * 61;
        u16* outp = y1b + ((long)(s0 + s) * NPS) * F_HID;
        {
            float a = al[10] * bf2f(hs[c]);
            #pragma unroll
            for (int j = 1; j <= 10; ++j) a += al[j-1] * bf2f(hs[j * F_HID + c]);
            outp[c] = f2bf(fmaxf(a + bc, 0.f));
        }
        #pragma unroll
        for (int j = 1; j <= 10; ++j) {
            int eb = 11 + 3*(j-1);
            float a = al[eb]   * bf2f(hs[c])
                    + al[eb+1] * bf2f(hs[(j+10) * F_HID + c])
                    + al[eb+2] * bf2f(hs[j * F_HID + c]);
            outp[j * F_HID + c] = f2bf(fmaxf(a + bc, 0.f));
        }
        #pragma unroll
        for (int j = 1; j <= 10; ++j) {
            int eb = 41 + 2*(j-1);
            float a = al[eb]   * bf2f(hs[j * F_HID + c])
                    + al[eb+1] * bf2f(hs[(10+j) * F_HID + c]);
            outp[(10+j) * F_HID + c] = f2bf(fmaxf(a + bc, 0.f));
        }
    }
}

// ------------------------------------------------------------------
// fused2: GEMM (63x256 @ W2b^T -> 63x128) + GAT agg layer 2 + readout.
// One block = 3 samples. Writes out_hid (fp32) + out_y.
// ------------------------------------------------------------------
__global__ __launch_bounds__(256) void fused2(const u16* __restrict__ y1b, const u16* __restrict__ W2b,
                                              const float* __restrict__ asrc, const float* __restrict__ adst,
                                              const float* __restrict__ bias,
                                              const float* __restrict__ Wl, const float* __restrict__ bl,
                                              float* __restrict__ out_hid, float* __restrict__ out_y)
{
    constexpr int KS  = 64;    // K per stage (256 = 4 stages)
    constexpr int SA  = 264;   // A row stride (256+8)
    constexpr int SB  = 72;
    __shared__ __align__(16) u16 Al[64 * SA];        // 33792 B; reused as hidwl (63*128 f32 = 32256 B)
    __shared__ __align__(16) u16 Bu[128 * SB];       // 18432 B: B stage, then h2 (64x128 bf16 = 16384 B)
    __shared__ float s_l[64], d_l[64], alpha[3 * 61];

    const int blk = blockIdx.x, tid = threadIdx.x;
    const int s0  = blk * SPB;
    const int nsamp = (s0 + SPB <= BATCH) ? SPB : (BATCH - s0);
    const int nrow  = nsamp * NPS;

    const int lane = tid & 63, w = tid >> 6;
    const int wr = w >> 1, wc = w & 1;
    const int lm = lane & 15, lq = lane >> 4;

    // ---- stage A (63x256 bf16 rows, zero-pad to 64) ----
    const u16* Ag = y1b + (long)s0 * NPS * F_HID;
    for (int id = tid; id < 64 * (F_HID / 8); id += 256) {  // 2048 chunks
        int row = id >> 5, ch = id & 31;
        uint4 v;
        if (row < nrow) v = *(const uint4*)(Ag + row * F_HID + ch * 8);
        else            v = make_uint4(0u, 0u, 0u, 0u);
        *(uint4*)(Al + row * SA + ch * 8) = v;
    }

    f32x4 acc[2][4];
    #pragma unroll
    for (int f = 0; f < 2; ++f)
        #pragma unroll
        for (int g = 0; g < 4; ++g)
            acc[f][g] = (f32x4){0.f, 0.f, 0.f, 0.f};

    for (int ks = 0; ks < F_HID; ks += KS) {
        __syncthreads();
        for (int id = tid; id < 128 * (KS / 8); id += 256) {  // 1024 chunks
            int row = id >> 3, ch = id & 7;
            *(uint4*)(Bu + row * SB + ch * 8) = *(const uint4*)(W2b + row * F_HID + ks + ch * 8);
        }
        __syncthreads();
        #pragma unroll
        for (int kb = 0; kb < KS / 32; ++kb) {
            int ka    = ks + kb * 32 + lq * 8;
            int kboff = kb * 32 + lq * 8;
            bf16x8 a0 = *(const bf16x8*)(Al + (wr*32 +  0 + lm) * SA + ka);
            bf16x8 a1 = *(const bf16x8*)(Al + (wr*32 + 16 + lm) * SA + ka);
            #pragma unroll
            for (int g = 0; g < 4; ++g) {
                bf16x8 b = *(const bf16x8*)(Bu + (wc*64 + g*16 + lm) * SB + kboff);
                acc[0][g] = __builtin_amdgcn_mfma_f32_16x16x32_bf16(a0, b, acc[0][g], 0, 0, 0);
                acc[1][g] = __builtin_amdgcn_mfma_f32_16x16x32_bf16(a1, b, acc[1][g], 0, 0, 0);
            }
        }
    }

    __syncthreads();          // Bu dead; reuse as h2
    u16* h2 = Bu;             // 64 x 128 bf16
    #pragma unroll
    for (int f = 0; f < 2; ++f)
        #pragma unroll
        for (int g = 0; g < 4; ++g)
            #pragma unroll
            for (int r = 0; r < 4; ++r) {
                int row = wr*32 + f*16 + lq*4 + r;
                int col = wc*64 + g*16 + lm;
                h2[row * F_OUT + col] = f2bf(acc[f][g][r]);
            }
    __syncthreads();

    // ---- attention logits over 128 features ----
    float av[2], dv[2];
    #pragma unroll
    for (int j = 0; j < 2; ++j) { av[j] = asrc[lane + j*64]; dv[j] = adst[lane + j*64]; }
    for (int n = w; n < nrow; n += 4) {
        float as_ = 0.f, ad_ = 0.f;
        #pragma unroll
        for (int j = 0; j < 2; ++j) {
            float hv = bf2f(h2[n * F_OUT + lane + j*64]);
            as_ += hv * av[j];
            ad_ += hv * dv[j];
        }
        as_ = wave_red(as_); ad_ = wave_red(ad_);
        if (lane == 0) { s_l[n] = as_; d_l[n] = ad_; }
    }
    __syncthreads();

    if (tid < nrow) {
        int s = tid / NPS, p = tid - s * NPS;
        int deg = deg_of(p), eb = edge_base(p);
        const float* sl = s_l + s * NPS;
        float dn = d_l[tid], m = -1e30f;
        for (int k = 0; k < deg; ++k) m = fmaxf(m, lrelu(sl[src_of(p,k)] + dn));
        float den = 0.f;
        for (int k = 0; k < deg; ++k) den += expf(lrelu(sl[src_of(p,k)] + dn) - m);
        float inv = 1.f / den;
        for (int k = 0; k < deg; ++k) alpha[s*61 + eb + k] = expf(lrelu(sl[src_of(p,k)] + dn) - m) * inv;
    }
    __syncthreads();

    // ---- aggregate + bias -> out_hid (fp32); stash relu(h)*Wl for readout ----
    float* hidwl = (float*)Al;     // Al dead after GEMM
    const int c    = tid & 127;
    const int half = tid >> 7;     // wave-uniform (waves 0-1 vs 2-3)
    float bc = bias[c];
    float wl = Wl[c];
    for (int s = 0; s < nsamp; ++s) {
        const u16* hs = h2 + s * NPS * F_OUT;
        const float* al = alpha + s * 61;
        long gb = (long)(s0 + s) * NPS * F_OUT;
        for (int p = half; p < NPS; p += 2) {
            int deg = deg_of(p), eb = edge_base(p);
            float a = 0.f;
            for (int k = 0; k < deg; ++k) a += al[eb + k] * bf2f(hs[src_of(p,k) * F_OUT + c]);
            float hv = a + bc;
            out_hid[gb + p * F_OUT + c] = hv;
            hidwl[(s * NPS + p) * F_OUT + c] = fmaxf(hv, 0.f) * wl;
        }
    }
    __syncthreads();

    // ---- readout: y = sigmoid(sum_c relu(hid)*Wl + bl) ----
    float bl0 = bl[0];
    for (int n = w; n < nrow; n += 4) {
        float v = hidwl[n * F_OUT + lane] + hidwl[n * F_OUT + lane + 64];
        v = wave_red(v);
        if (lane == 0) out_y[(long)s0 * NPS + n] = 1.f / (1.f + expf(-(v + bl0)));
    }
}

// ------------------------------------------------------------------
extern "C" void kernel_launch(void* const* d_in, const int* in_sizes, int n_in,
                              void* d_out, int out_size, void* d_ws, size_t ws_size,
                              hipStream_t stream) {
    const int*   ip    = (const int*)  d_in[0];
    const float* x     = (const float*)d_in[1];
    const int*   click = (const int*)  d_in[4];
    const int*   query = (const int*)  d_in[5];
    const int*   docu  = (const int*)  d_in[6];
    const int*   title = (const int*)  d_in[7];
    const float* qtab  = (const float*)d_in[8];
    const float* dtab  = (const float*)d_in[9];
    const float* ttab  = (const float*)d_in[10];
    const float* ptab  = (const float*)d_in[11];
    const float* ctab  = (const float*)d_in[12];
    const float* W1    = (const float*)d_in[13];
    const float* as1   = (const float*)d_in[14];
    const float* ad1   = (const float*)d_in[15];
    const float* b1    = (const float*)d_in[16];
    const float* W2    = (const float*)d_in[17];
    const float* as2   = (const float*)d_in[18];
    const float* ad2   = (const float*)d_in[19];
    const float* b2    = (const float*)d_in[20];
    const float* Wl    = (const float*)d_in[21];
    const float* bl    = (const float*)d_in[22];

    float* out_hid = (float*)d_out;
    float* out_y   = out_hid + (long)N_NODES * F_OUT;
    float* out_x   = out_y + N_NODES;

    u16* xb  = (u16*)d_ws;                       // 8192*4032      = 33,030,144 u16
    u16* y1b = xb + (long)BATCH * SXB;           // 172032*256     = 44,040,192 u16
    u16* W1b = y1b + (long)N_NODES * F_HID;      // 49,152 u16
    u16* W2b = W1b + 256 * K1P;                  // 32,768 u16

    build_x<<<BATCH + 192, 256, 0, stream>>>(ip, x, click, query, docu, title,
                                             qtab, dtab, ttab, ptab, ctab,
                                             W1, W2, out_x, xb, W1b, W2b);
    fused1<<<NBLK, 256, 0, stream>>>(xb, W1b, as1, ad1, b1, y1b);
    fused2<<<NBLK, 256, 0, stream>>>(y1b, W2b, as2, ad2, b2, Wl, bl, out_hid, out_y);
}

// Round 3
// 571.129 us; speedup vs baseline: 1.1302x; 1.1302x over previous
//
#include <hip/hip_runtime.h>
#include <cstdint>

#define N_NODES 172032
#define BATCH   8192
#define NPS     21
#define F_IN    171
#define K1P     192      // K padded to multiple of 32 for layer-1 GEMM
#define F_HID   256
#define F_OUT   128
#define SX_F    (NPS * F_IN)   // 3591 floats per sample in x/out_x
#define SXP     172            // padded sx row stride (floats) for aligned float4
#define SXB     (NPS * K1P)    // 4032 bf16 per sample in xb
#define SPB     3              // samples per fused block
#define NBLK    2731           // ceil(8192/3)

typedef unsigned short u16;
typedef __attribute__((ext_vector_type(8))) short  bf16x8;
typedef __attribute__((ext_vector_type(4))) float  f32x4;

__device__ inline u16 f2bf(float f) {
    unsigned u = __float_as_uint(f);
    unsigned r = u + 0x7FFFu + ((u >> 16) & 1u);
    return (u16)(r >> 16);
}
__device__ inline float bf2f(u16 h) { return __uint_as_float(((unsigned)h) << 16); }
__device__ inline float lrelu(float v) { return v > 0.f ? v : 0.2f * v; }

// ---- static edge structure (local node ids within a 21-node sample) ----
// node 0 = query, 1..10 = docs, 11..20 = titles
__device__ inline int deg_of(int n)  { return n == 0 ? 11 : (n <= 10 ? 3 : 2); }
__device__ inline int edge_base(int n) { return n == 0 ? 0 : (n <= 10 ? 11 + 3*(n-1) : 41 + 2*(n-11)); }
__device__ inline int src_of(int n, int k) {
    if (n == 0)  return k < 10 ? k + 1 : 0;
    if (n <= 10) return k == 0 ? 0 : (k == 1 ? n + 10 : n);
    return k == 0 ? n - 10 : n;
}

__device__ inline float wave_red(float v) {
    for (int off = 32; off; off >>= 1) v += __shfl_down(v, off);
    return v;
}

// ------------------------------------------------------------------
// build_x: one block per SAMPLE (blocks < BATCH). Assemble 21x171 fp32
// in LDS (row stride 172 for aligned float4) from table gathers + x
// tail, then bulk write: out_x via aligned float4, xb via 8xbf16 uint4.
// Blocks >= BATCH: weight prep (W1->W1b 256x192 bf16, W2->W2b bf16).
// ------------------------------------------------------------------
__global__ __launch_bounds__(256) void build_x(const int* __restrict__ iptr, const float* __restrict__ x,
                        const int* __restrict__ click, const int* __restrict__ query,
                        const int* __restrict__ docu, const int* __restrict__ title_id,
                        const float* __restrict__ qtab, const float* __restrict__ dtab,
                        const float* __restrict__ ttab, const float* __restrict__ ptab,
                        const float* __restrict__ ctab,
                        const float* __restrict__ W1, const float* __restrict__ W2,
                        float* __restrict__ out_x, u16* __restrict__ xb,
                        u16* __restrict__ W1b, u16* __restrict__ W2b)
{
    if (blockIdx.x >= BATCH) {
        int id = (blockIdx.x - BATCH) * 256 + threadIdx.x;
        if (id < 256 * K1P) {
            int r = id / K1P, k = id - r * K1P;
            W1b[id] = (k < F_IN) ? f2bf(W1[r * F_IN + k]) : (u16)0;
        }
        if (id < 128 * 256) W2b[id] = f2bf(W2[id]);
        return;
    }

    __shared__ float sx[NPS * SXP];
    __shared__ int   dz[10], tz[10], s_q;
    __shared__ float s_clk;

    const int s   = blockIdx.x;
    const int tid = threadIdx.x;
    const int i   = iptr[0];
    const long xbase = (long)s * SX_F;

    if (tid < 10)       dz[tid]      = docu[s*10 + tid];
    else if (tid < 20)  tz[tid - 10] = title_id[s*10 + tid - 10];
    else if (tid == 20) s_q          = query[s];
    else if (tid == 21) s_clk        = ctab[click[s]];
    __syncthreads();

    if (i == 0) {
        // cols 0..159: table rows are 160 floats = 640 B, 16B-aligned -> float4
        for (int id = tid; id < NPS * 40; id += 256) {
            int p = id / 40, c4 = (id - p * 40) * 4;
            const float* src;
            if (p == 0)       src = qtab + (long)s_q * 160;
            else if (p <= 10) src = dtab + (long)dz[p-1] * 160;
            else              src = ttab + (long)tz[p-11] * 160;
            *(float4*)(sx + p * SXP + c4) = *(const float4*)(src + c4);
        }
        // cols 160..170: specials + x tail
        for (int id = tid; id < NPS * 11; id += 256) {
            int p = id / 11, c = 160 + (id - p * 11);
            float v;
            if (p >= 1 && p <= 10 && c == 160)      v = ptab[p - 1];
            else if (p >= 1 && p <= 10 && c == 161) v = s_clk;
            else                                     v = x[xbase + p * F_IN + c];
            sx[p * SXP + c] = v;
        }
    } else {
        for (int idx = tid; idx < SX_F; idx += 256) {
            int p = idx / F_IN;
            int c = idx - p * F_IN;
            float v = x[xbase + idx];
            if (p >= 1 && p <= 10 && c == 161 + i) v = s_clk;
            sx[p * SXP + c] = v;
        }
    }
    __syncthreads();

    // ---- out_x: flat region [xbase, xbase+3591), float4 on aligned interior ----
    {
        int r    = (int)(xbase & 3);
        int head = (4 - r) & 3;
        if (tid < head) {
            int p = tid / F_IN, c = tid - p * F_IN;
            out_x[xbase + tid] = sx[p * SXP + c];
        }
        int n4 = (SX_F - head) >> 2;
        for (int id = tid; id < n4; id += 256) {
            int o = head + id * 4;
            float4 v;
            {
                int p0 = o / F_IN, c0 = o - p0 * F_IN;
                v.x = sx[p0 * SXP + c0];
                int o1 = o + 1; int p1 = o1 / F_IN, c1 = o1 - p1 * F_IN;
                v.y = sx[p1 * SXP + c1];
                int o2 = o + 2; int p2 = o2 / F_IN, c2 = o2 - p2 * F_IN;
                v.z = sx[p2 * SXP + c2];
                int o3 = o + 3; int p3 = o3 / F_IN, c3 = o3 - p3 * F_IN;
                v.w = sx[p3 * SXP + c3];
            }
            *(float4*)(out_x + xbase + o) = v;
        }
        int done = head + n4 * 4;
        int tail = SX_F - done;
        if (tid < tail) {
            int idx = done + tid;
            int p = idx / F_IN, c = idx - p * F_IN;
            out_x[xbase + idx] = sx[p * SXP + c];
        }
    }

    // ---- xb: bf16, K-padded to 192/row; sample region 16B-aligned ----
    {
        u16* xbs = xb + (long)s * SXB;
        for (int id = tid; id < SXB / 8; id += 256) {
            int k0 = id * 8;
            int node = k0 / K1P;
            int kk   = k0 - node * K1P;
            union { u16 h[8]; uint4 v; } u;
            #pragma unroll
            for (int j = 0; j < 8; ++j) {
                int c = kk + j;
                u.h[j] = (c < F_IN) ? f2bf(sx[node * SXP + c]) : (u16)0;
            }
            *(uint4*)(xbs + k0) = u.v;
        }
    }
}

// ------------------------------------------------------------------
// fused1 v2: GEMM (64x192 @ W1b^T -> 64x256) + GAT agg layer 1 + relu.
// One block = 3 samples. B read per-fragment from global (L2-hot,
// 96 KB shared by all blocks). h unions with A-tile in LDS (34.5 KB ->
// 4 blocks/CU). Attention logits computed in-register from acc.
// 4 barriers total.
// ------------------------------------------------------------------
__global__ __launch_bounds__(256, 4) void fused1(const u16* __restrict__ xb, const u16* __restrict__ W1b,
                                                 const float* __restrict__ asrc, const float* __restrict__ adst,
                                                 const float* __restrict__ bias, u16* __restrict__ y1b)
{
    constexpr int SA = 200;                       // A row stride (u16), 400 B = 25*16
    __shared__ __align__(16) u16 hbuf[64 * 256];  // 32 KB: A-tile (64xSA), then h (64x256)
    __shared__ float s_part[2][64], d_part[2][64];
    __shared__ float alpha[SPB * 61];

    const int blk = blockIdx.x, tid = threadIdx.x;
    const int s0  = blk * SPB;
    const int nsamp = (s0 + SPB <= BATCH) ? SPB : (BATCH - s0);
    const int nrow  = nsamp * NPS;

    const int lane = tid & 63, w = tid >> 6;
    const int wr = w >> 1, wc = w & 1;
    const int lm = lane & 15, lq = lane >> 4;

    // ---- stage A (nrow x 192 bf16 rows, zero-pad to 64) ----
    const u16* Ag = xb + (long)s0 * SXB;
    for (int id = tid; id < 64 * 24; id += 256) {
        int row = id / 24, ch = id - row * 24;
        uint4 v;
        if (row < nrow) v = *(const uint4*)(Ag + row * K1P + ch * 8);
        else            v = make_uint4(0u, 0u, 0u, 0u);
        *(uint4*)(hbuf + row * SA + ch * 8) = v;
    }
    __syncthreads();

    f32x4 acc[2][8];
    #pragma unroll
    for (int f = 0; f < 2; ++f)
        #pragma unroll
        for (int g = 0; g < 8; ++g)
            acc[f][g] = (f32x4){0.f, 0.f, 0.f, 0.f};

    #pragma unroll
    for (int kb = 0; kb < K1P / 32; ++kb) {
        int koff = kb * 32 + lq * 8;
        bf16x8 a0 = *(const bf16x8*)(hbuf + (wr*32 +  0 + lm) * SA + koff);
        bf16x8 a1 = *(const bf16x8*)(hbuf + (wr*32 + 16 + lm) * SA + koff);
        #pragma unroll
        for (int g = 0; g < 8; ++g) {
            bf16x8 b = *(const bf16x8*)(W1b + (wc*128 + g*16 + lm) * K1P + koff);
            acc[0][g] = __builtin_amdgcn_mfma_f32_16x16x32_bf16(a0, b, acc[0][g], 0, 0, 0);
            acc[1][g] = __builtin_amdgcn_mfma_f32_16x16x32_bf16(a1, b, acc[1][g], 0, 0, 0);
        }
    }
    __syncthreads();          // all waves done reading A before h overwrite

    // ---- h write + in-register attention-logit partials ----
    u16* h = hbuf;            // 64 rows x 256 cols bf16
    float av[8], dv[8];
    #pragma unroll
    for (int g = 0; g < 8; ++g) {
        av[g] = asrc[wc*128 + g*16 + lm];
        dv[g] = adst[wc*128 + g*16 + lm];
    }
    #pragma unroll
    for (int f = 0; f < 2; ++f)
        #pragma unroll
        for (int r = 0; r < 4; ++r) {
            int row = wr*32 + f*16 + lq*4 + r;
            float sp = 0.f, dp = 0.f;
            #pragma unroll
            for (int g = 0; g < 8; ++g) {
                float v = acc[f][g][r];
                h[row * F_HID + wc*128 + g*16 + lm] = f2bf(v);
                sp += v * av[g];
                dp += v * dv[g];
            }
            #pragma unroll
            for (int off = 1; off < 16; off <<= 1) {
                sp += __shfl_xor(sp, off);
                dp += __shfl_xor(dp, off);
            }
            if (lm == 0) { s_part[wc][row] = sp; d_part[wc][row] = dp; }
        }
    __syncthreads();

    // ---- softmax over incoming edges (per destination node) ----
    if (tid < nrow) {
        int s = tid / NPS, p = tid - s * NPS;
        int deg = deg_of(p), eb = edge_base(p);
        int sb = s * NPS;
        float dn = d_part[0][tid] + d_part[1][tid];
        float e[11];
        float m = -1e30f;
        for (int k = 0; k < deg; ++k) {
            int sn = sb + src_of(p, k);
            e[k] = lrelu(s_part[0][sn] + s_part[1][sn] + dn);
            m = fmaxf(m, e[k]);
        }
        float den = 0.f;
        for (int k = 0; k < deg; ++k) { e[k] = expf(e[k] - m); den += e[k]; }
        float inv = 1.f / den;
        for (int k = 0; k < deg; ++k) alpha[s*61 + eb + k] = e[k] * inv;
    }
    __syncthreads();

    // ---- aggregate + bias + relu -> y1b (bf16) ----
    const int c = tid;          // 256 threads = F_HID
    float bc = bias[c];
    for (int s = 0; s < nsamp; ++s) {
        const u16* hs = h + s * NPS * F_HID;
        const float* al = alpha + s * 61;
        u16* outp = y1b + ((long)(s0 + s) * NPS) * F_HID;
        {
            float a = al[10] * bf2f(hs[c]);
            #pragma unroll
            for (int j = 1; j <= 10; ++j) a += al[j-1] * bf2f(hs[j * F_HID + c]);
            outp[c] = f2bf(fmaxf(a + bc, 0.f));
        }
        #pragma unroll
        for (int j = 1; j <= 10; ++j) {
            int eb = 11 + 3*(j-1);
            float a = al[eb]   * bf2f(hs[c])
                    + al[eb+1] * bf2f(hs[(j+10) * F_HID + c])
                    + al[eb+2] * bf2f(hs[j * F_HID + c]);
            outp[j * F_HID + c] = f2bf(fmaxf(a + bc, 0.f));
        }
        #pragma unroll
        for (int j = 1; j <= 10; ++j) {
            int eb = 41 + 2*(j-1);
            float a = al[eb]   * bf2f(hs[j * F_HID + c])
                    + al[eb+1] * bf2f(hs[(10+j) * F_HID + c]);
            outp[(10+j) * F_HID + c] = f2bf(fmaxf(a + bc, 0.f));
        }
    }
}

// ------------------------------------------------------------------
// fused2 v2: GEMM (64x256 @ W2b^T -> 64x128) + GAT agg layer 2 +
// readout. Same structure as fused1 v2. Writes out_hid (fp32) + out_y.
// ------------------------------------------------------------------
__global__ __launch_bounds__(256, 4) void fused2(const u16* __restrict__ y1b, const u16* __restrict__ W2b,
                                                 const float* __restrict__ asrc, const float* __restrict__ adst,
                                                 const float* __restrict__ bias,
                                                 const float* __restrict__ Wl, const float* __restrict__ bl,
                                                 float* __restrict__ out_hid, float* __restrict__ out_y)
{
    constexpr int SA = 264;                       // A row stride (u16), 528 B = 33*16
    __shared__ __align__(16) u16 hbuf[64 * SA];   // 33.8 KB: A-tile, then h2 (64x128)
    __shared__ float s_part[2][64], d_part[2][64];
    __shared__ float alpha[SPB * 61];
    __shared__ float rpart[SPB * NPS][2];

    const int blk = blockIdx.x, tid = threadIdx.x;
    const int s0  = blk * SPB;
    const int nsamp = (s0 + SPB <= BATCH) ? SPB : (BATCH - s0);
    const int nrow  = nsamp * NPS;

    const int lane = tid & 63, w = tid >> 6;
    const int wr = w >> 1, wc = w & 1;
    const int lm = lane & 15, lq = lane >> 4;

    // ---- stage A (nrow x 256 bf16 rows, zero-pad to 64) ----
    const u16* Ag = y1b + (long)s0 * NPS * F_HID;
    for (int id = tid; id < 64 * 32; id += 256) {
        int row = id >> 5, ch = id & 31;
        uint4 v;
        if (row < nrow) v = *(const uint4*)(Ag + row * F_HID + ch * 8);
        else            v = make_uint4(0u, 0u, 0u, 0u);
        *(uint4*)(hbuf + row * SA + ch * 8) = v;
    }
    __syncthreads();

    f32x4 acc[2][4];
    #pragma unroll
    for (int f = 0; f < 2; ++f)
        #pragma unroll
        for (int g = 0; g < 4; ++g)
            acc[f][g] = (f32x4){0.f, 0.f, 0.f, 0.f};

    #pragma unroll
    for (int kb = 0; kb < F_HID / 32; ++kb) {
        int koff = kb * 32 + lq * 8;
        bf16x8 a0 = *(const bf16x8*)(hbuf + (wr*32 +  0 + lm) * SA + koff);
        bf16x8 a1 = *(const bf16x8*)(hbuf + (wr*32 + 16 + lm) * SA + koff);
        #pragma unroll
        for (int g = 0; g < 4; ++g) {
            bf16x8 b = *(const bf16x8*)(W2b + (wc*64 + g*16 + lm) * F_HID + koff);
            acc[0][g] = __builtin_amdgcn_mfma_f32_16x16x32_bf16(a0, b, acc[0][g], 0, 0, 0);
            acc[1][g] = __builtin_amdgcn_mfma_f32_16x16x32_bf16(a1, b, acc[1][g], 0, 0, 0);
        }
    }
    __syncthreads();          // all waves done reading A before h2 overwrite

    // ---- h2 write + in-register attention-logit partials ----
    u16* h2 = hbuf;           // 64 x 128 bf16
    float av[4], dv[4];
    #pragma unroll
    for (int g = 0; g < 4; ++g) {
        av[g] = asrc[wc*64 + g*16 + lm];
        dv[g] = adst[wc*64 + g*16 + lm];
    }
    #pragma unroll
    for (int f = 0; f < 2; ++f)
        #pragma unroll
        for (int r = 0; r < 4; ++r) {
            int row = wr*32 + f*16 + lq*4 + r;
            float sp = 0.f, dp = 0.f;
            #pragma unroll
            for (int g = 0; g < 4; ++g) {
                float v = acc[f][g][r];
                h2[row * F_OUT + wc*64 + g*16 + lm] = f2bf(v);
                sp += v * av[g];
                dp += v * dv[g];
            }
            #pragma unroll
            for (int off = 1; off < 16; off <<= 1) {
                sp += __shfl_xor(sp, off);
                dp += __shfl_xor(dp, off);
            }
            if (lm == 0) { s_part[wc][row] = sp; d_part[wc][row] = dp; }
        }
    __syncthreads();

    // ---- softmax ----
    if (tid < nrow) {
        int s = tid / NPS, p = tid - s * NPS;
        int deg = deg_of(p), eb = edge_base(p);
        int sb = s * NPS;
        float dn = d_part[0][tid] + d_part[1][tid];
        float e[11];
        float m = -1e30f;
        for (int k = 0; k < deg; ++k) {
            int sn = sb + src_of(p, k);
            e[k] = lrelu(s_part[0][sn] + s_part[1][sn] + dn);
            m = fmaxf(m, e[k]);
        }
        float den = 0.f;
        for (int k = 0; k < deg; ++k) { e[k] = expf(e[k] - m); den += e[k]; }
        float inv = 1.f / den;
        for (int k = 0; k < deg; ++k) alpha[s*61 + eb + k] = e[k] * inv;
    }
    __syncthreads();

    // ---- aggregate + bias -> out_hid; per-row wave partials for readout ----
    const int c    = tid & 127;
    const int half = tid >> 7;     // wave-uniform (waves 0-1 vs 2-3)
    float bc = bias[c];
    float wl = Wl[c];
    for (int s = 0; s < nsamp; ++s) {
        const u16* hs = h2 + s * NPS * F_OUT;
        const float* al = alpha + s * 61;
        long gb = (long)(s0 + s) * NPS * F_OUT;
        for (int p = half; p < NPS; p += 2) {
            int deg = deg_of(p), eb = edge_base(p);
            float a = 0.f;
            for (int k = 0; k < deg; ++k) a += al[eb + k] * bf2f(hs[src_of(p,k) * F_OUT + c]);
            float hv = a + bc;
            out_hid[gb + p * F_OUT + c] = hv;
            float rv = wave_red(fmaxf(hv, 0.f) * wl);
            if (lane == 0) rpart[s * NPS + p][w & 1] = rv;
        }
    }
    __syncthreads();

    // ---- readout: y = sigmoid(sum_c relu(hid)*Wl + bl) ----
    if (tid < nrow) {
        float v = rpart[tid][0] + rpart[tid][1] + bl[0];
        out_y[(long)s0 * NPS + tid] = 1.f / (1.f + expf(-v));
    }
}

// ------------------------------------------------------------------
extern "C" void kernel_launch(void* const* d_in, const int* in_sizes, int n_in,
                              void* d_out, int out_size, void* d_ws, size_t ws_size,
                              hipStream_t stream) {
    const int*   ip    = (const int*)  d_in[0];
    const float* x     = (const float*)d_in[1];
    const int*   click = (const int*)  d_in[4];
    const int*   query = (const int*)  d_in[5];
    const int*   docu  = (const int*)  d_in[6];
    const int*   title = (const int*)  d_in[7];
    const float* qtab  = (const float*)d_in[8];
    const float* dtab  = (const float*)d_in[9];
    const float* ttab  = (const float*)d_in[10];
    const float* ptab  = (const float*)d_in[11];
    const float* ctab  = (const float*)d_in[12];
    const float* W1    = (const float*)d_in[13];
    const float* as1   = (const float*)d_in[14];
    const float* ad1   = (const float*)d_in[15];
    const float* b1    = (const float*)d_in[16];
    const float* W2    = (const float*)d_in[17];
    const float* as2   = (const float*)d_in[18];
    const float* ad2   = (const float*)d_in[19];
    const float* b2    = (const float*)d_in[20];
    const float* Wl    = (const float*)d_in[21];
    const float* bl    = (const float*)d_in[22];

    float* out_hid = (float*)d_out;
    float* out_y   = out_hid + (long)N_NODES * F_OUT;
    float* out_x   = out_y + N_NODES;

    u16* xb  = (u16*)d_ws;                       // 8192*4032      = 33,030,144 u16
    u16* y1b = xb + (long)BATCH * SXB;           // 172032*256     = 44,040,192 u16
    u16* W1b = y1b + (long)N_NODES * F_HID;      // 49,152 u16
    u16* W2b = W1b + 256 * K1P;                  // 32,768 u16

    build_x<<<BATCH + 192, 256, 0, stream>>>(ip, x, click, query, docu, title,
                                             qtab, dtab, ttab, ptab, ctab,
                                             W1, W2, out_x, xb, W1b, W2b);
    fused1<<<NBLK, 256, 0, stream>>>(xb, W1b, as1, ad1, b1, y1b);
    fused2<<<NBLK, 256, 0, stream>>>(y1b, W2b, as2, ad2, b2, Wl, bl, out_hid, out_y);
}